// Round 3
// baseline (1105.861 us; speedup 1.0000x reference)
//
#include <hip/hip_runtime.h>
#include <hip/hip_bf16.h>

#define WIN 7
#define DISPL 3
#define NHEADS 6
#define HD 32
#define HH 224
#define WWID 224
#define NB 2
#define MROWS (NB*HH*WWID)   // 100352

typedef __attribute__((ext_vector_type(8))) short short8v;
typedef __attribute__((ext_vector_type(4))) float f32x4;

__device__ __forceinline__ float b2f(unsigned short u) {
    unsigned v = ((unsigned)u) << 16;
    return __builtin_bit_cast(float, v);
}
__device__ __forceinline__ unsigned short f2b(float f) {
    unsigned u = __builtin_bit_cast(unsigned, f);
    unsigned r = (u + 0x7FFFu + ((u >> 16) & 1u)) >> 16;
    return (unsigned short)r;
}

__device__ __forceinline__ void gload_lds16(const unsigned short* g, unsigned short* l) {
    __builtin_amdgcn_global_load_lds(
        (const __attribute__((address_space(1))) unsigned*)(g),
        (__attribute__((address_space(3))) unsigned*)(l),
        16, 0, 0);
}

// ---------------- weight convert + transpose: W[K][N] f32 -> Wt[N][K] bf16 ---
__global__ void wt_k(const float* __restrict__ W, unsigned short* __restrict__ Wt,
                     int Kk, int Nn) {
    int idx = blockIdx.x * 256 + threadIdx.x;
    if (idx >= Kk * Nn) return;
    int n = idx % Nn, k = idx / Nn;
    Wt[(size_t)n * Kk + k] = f2b(W[idx]);
}

// =====================================================================
// Generic GEMM: C[M][N] = A[M][K](bf16) * Bt[N][K](bf16) + epilogue
// BM=128, BN=192, BK=32; 256 threads = 4 waves (2x2), wave-tile 64x96.
// EPI: 0 = plain bf16 out, 1 = bias+GELU bf16 out,
//      2 = tbuf(f32, +bias+resid) + fused LayerNorm -> y bf16,
//      3 = tbuf(f32, +bias+resid) only.
// =====================================================================
template<int EPI, int BIAS, int RES>
__global__ __launch_bounds__(256) void gemm_k(const unsigned short* __restrict__ A,
                                              const unsigned short* __restrict__ Bt,
                                              const float* __restrict__ bias,
                                              const float* __restrict__ resid,
                                              const float* __restrict__ lng,
                                              const float* __restrict__ lnb,
                                              float* __restrict__ tout,
                                              unsigned short* __restrict__ yout,
                                              int Nn, int Kk) {
    __shared__ unsigned short Asm_[128 * 32];
    __shared__ unsigned short Bsm[192 * 32];
    __shared__ float ssum[128][2], ssq[128][2];
    int t = threadIdx.x, lane = t & 63, w = t >> 6;
    int iq = lane & 15, hi = lane >> 4;
    int wr = w >> 1, wc = w & 1;
    int m0 = blockIdx.y * 128, n0 = blockIdx.x * 192;
    f32x4 acc[4][6] = {};
    int nsteps = Kk >> 5;
    int lrow = lane >> 2, lseg = lane & 3;
    for (int kk = 0; kk < nsteps; kk++) {
        __syncthreads();
        #pragma unroll
        for (int i = 0; i < 5; i++) {
            int q = w * 5 + i;                       // 0..19
            if (q < 8) {
                int row = q * 16 + lrow;
                gload_lds16(A + (size_t)(m0 + row) * Kk + kk * 32 + lseg * 8,
                            &Asm_[q * 512]);
            } else {
                int nr = (q - 8) * 16 + lrow;
                gload_lds16(Bt + (size_t)(n0 + nr) * Kk + kk * 32 + lseg * 8,
                            &Bsm[(q - 8) * 512]);
            }
        }
        __syncthreads();
        short8v af[4], bf[6];
        #pragma unroll
        for (int mt = 0; mt < 4; mt++)
            af[mt] = *(const short8v*)&Asm_[(wr * 64 + 16 * mt + iq) * 32 + hi * 8];
        #pragma unroll
        for (int nt = 0; nt < 6; nt++)
            bf[nt] = *(const short8v*)&Bsm[(wc * 96 + 16 * nt + iq) * 32 + hi * 8];
        #pragma unroll
        for (int mt = 0; mt < 4; mt++)
            #pragma unroll
            for (int nt = 0; nt < 6; nt++)
                acc[mt][nt] = __builtin_amdgcn_mfma_f32_16x16x32_bf16(af[mt], bf[nt], acc[mt][nt], 0, 0, 0);
    }

    // epilogue
    float bv[6];
    int colg[6];
    #pragma unroll
    for (int nt = 0; nt < 6; nt++) {
        colg[nt] = n0 + wc * 96 + 16 * nt + iq;
        bv[nt] = BIAS ? bias[colg[nt]] : 0.0f;
    }

    if (EPI <= 1) {
        #pragma unroll
        for (int mt = 0; mt < 4; mt++)
            #pragma unroll
            for (int rr = 0; rr < 4; rr++) {
                size_t row = m0 + wr * 64 + 16 * mt + 4 * hi + rr;
                #pragma unroll
                for (int nt = 0; nt < 6; nt++) {
                    float v = acc[mt][nt][rr] + bv[nt];
                    if (EPI == 1) v = 0.5f * v * (1.0f + erff(v * 0.70710678118654752f));
                    yout[row * Nn + colg[nt]] = f2b(v);
                }
            }
    } else {
        // tbuf = bias + resid + C (f32)
        #pragma unroll
        for (int mt = 0; mt < 4; mt++)
            #pragma unroll
            for (int rr = 0; rr < 4; rr++) {
                size_t row = m0 + wr * 64 + 16 * mt + 4 * hi + rr;
                #pragma unroll
                for (int nt = 0; nt < 6; nt++) {
                    float v = acc[mt][nt][rr] + bv[nt];
                    if (RES) v += resid[row * 192 + colg[nt]];
                    acc[mt][nt][rr] = v;
                    tout[row * 192 + colg[nt]] = v;
                }
            }
        if (EPI == 2) {
            #pragma unroll
            for (int mt = 0; mt < 4; mt++)
                #pragma unroll
                for (int rr = 0; rr < 4; rr++) {
                    float s = 0.f, sq = 0.f;
                    #pragma unroll
                    for (int nt = 0; nt < 6; nt++) {
                        float v = acc[mt][nt][rr];
                        s += v; sq += v * v;
                    }
                    #pragma unroll
                    for (int o = 1; o < 16; o <<= 1) {
                        s += __shfl_xor(s, o); sq += __shfl_xor(sq, o);
                    }
                    if (iq == 0) {
                        int rl = wr * 64 + 16 * mt + 4 * hi + rr;
                        ssum[rl][wc] = s; ssq[rl][wc] = sq;
                    }
                }
            float lgv[6], lbv[6];
            #pragma unroll
            for (int nt = 0; nt < 6; nt++) { lgv[nt] = lng[colg[nt]]; lbv[nt] = lnb[colg[nt]]; }
            __syncthreads();
            #pragma unroll
            for (int mt = 0; mt < 4; mt++)
                #pragma unroll
                for (int rr = 0; rr < 4; rr++) {
                    int rl = wr * 64 + 16 * mt + 4 * hi + rr;
                    float mean = (ssum[rl][0] + ssum[rl][1]) * (1.f / 192.f);
                    float var = (ssq[rl][0] + ssq[rl][1]) * (1.f / 192.f) - mean * mean;
                    float rstd = rsqrtf(var + 1e-5f);
                    size_t row = m0 + rl;
                    #pragma unroll
                    for (int nt = 0; nt < 6; nt++) {
                        float v = (acc[mt][nt][rr] - mean) * rstd * lgv[nt] + lbv[nt];
                        yout[row * 192 + colg[nt]] = f2b(v);
                    }
                }
        }
    }
}

// =====================================================================
// PatchMerge GEMM: fused unfold(x) @ pm_w + bias, then LN -> y.
// A staged from x f32 with on-the-fly bf16 convert; B via global_load_lds.
// BM=128, BN=192 (full), K=384.
// =====================================================================
__global__ __launch_bounds__(256) void pm_gemm_k(const float* __restrict__ x,
                                                 const unsigned short* __restrict__ Bt,
                                                 const float* __restrict__ bias,
                                                 const float* __restrict__ lng,
                                                 const float* __restrict__ lnb,
                                                 float* __restrict__ tout,
                                                 unsigned short* __restrict__ yout) {
    __shared__ unsigned short Asm_[128 * 32];
    __shared__ unsigned short Bsm[192 * 32];
    __shared__ float ssum[128][2], ssq[128][2];
    int t = threadIdx.x, lane = t & 63, w = t >> 6;
    int iq = lane & 15, hi = lane >> 4;
    int wr = w >> 1, wc = w & 1;
    int m0 = blockIdx.x * 128;
    f32x4 acc[4][6] = {};
    // per-thread fixed source row
    int row = t & 127;
    int m = m0 + row;
    int j = m % 224; int bi = m / 224; int i = bi % 224; int b = bi / 224;
    size_t xbase = ((size_t)b * 96 * 448 + 2 * i) * 448 + 2 * j;
    int s0 = t >> 7;   // 0 or 1
    int lrow = lane >> 2, lseg = lane & 3;
    for (int kk = 0; kk < 12; kk++) {
        __syncthreads();
        // A-stage: 16 (c,p1) segments x 2 (p2) per k-step, 8 iters/thread
        #pragma unroll
        for (int it = 0; it < 8; it++) {
            int s = s0 + 2 * it;          // 0..15
            int c = 8 * kk + (s >> 1);
            int p1 = s & 1;
            float2 xv = *(const float2*)(x + xbase + (size_t)c * 200704 + p1 * 448);
            ushort2 o; o.x = f2b(xv.x); o.y = f2b(xv.y);
            *(ushort2*)&Asm_[row * 32 + 2 * s] = o;
        }
        // B-stage: 12 x 1KB issues, 3 per wave
        #pragma unroll
        for (int i2 = 0; i2 < 3; i2++) {
            int q = w * 3 + i2;
            int nr = q * 16 + lrow;
            gload_lds16(Bt + (size_t)nr * 384 + kk * 32 + lseg * 8, &Bsm[q * 512]);
        }
        __syncthreads();
        short8v af[4], bf[6];
        #pragma unroll
        for (int mt = 0; mt < 4; mt++)
            af[mt] = *(const short8v*)&Asm_[(wr * 64 + 16 * mt + iq) * 32 + hi * 8];
        #pragma unroll
        for (int nt = 0; nt < 6; nt++)
            bf[nt] = *(const short8v*)&Bsm[(wc * 96 + 16 * nt + iq) * 32 + hi * 8];
        #pragma unroll
        for (int mt = 0; mt < 4; mt++)
            #pragma unroll
            for (int nt = 0; nt < 6; nt++)
                acc[mt][nt] = __builtin_amdgcn_mfma_f32_16x16x32_bf16(af[mt], bf[nt], acc[mt][nt], 0, 0, 0);
    }
    // epilogue: bias -> tbuf f32 + LN -> y
    float bv[6]; int colg[6];
    #pragma unroll
    for (int nt = 0; nt < 6; nt++) {
        colg[nt] = wc * 96 + 16 * nt + iq;
        bv[nt] = bias[colg[nt]];
    }
    #pragma unroll
    for (int mt = 0; mt < 4; mt++)
        #pragma unroll
        for (int rr = 0; rr < 4; rr++) {
            size_t rowg = m0 + wr * 64 + 16 * mt + 4 * hi + rr;
            #pragma unroll
            for (int nt = 0; nt < 6; nt++) {
                float v = acc[mt][nt][rr] + bv[nt];
                acc[mt][nt][rr] = v;
                tout[rowg * 192 + colg[nt]] = v;
            }
        }
    #pragma unroll
    for (int mt = 0; mt < 4; mt++)
        #pragma unroll
        for (int rr = 0; rr < 4; rr++) {
            float s = 0.f, sq = 0.f;
            #pragma unroll
            for (int nt = 0; nt < 6; nt++) { float v = acc[mt][nt][rr]; s += v; sq += v * v; }
            #pragma unroll
            for (int o = 1; o < 16; o <<= 1) { s += __shfl_xor(s, o); sq += __shfl_xor(sq, o); }
            if (iq == 0) {
                int rl = wr * 64 + 16 * mt + 4 * hi + rr;
                ssum[rl][wc] = s; ssq[rl][wc] = sq;
            }
        }
    float lgv[6], lbv[6];
    #pragma unroll
    for (int nt = 0; nt < 6; nt++) { lgv[nt] = lng[colg[nt]]; lbv[nt] = lnb[colg[nt]]; }
    __syncthreads();
    #pragma unroll
    for (int mt = 0; mt < 4; mt++)
        #pragma unroll
        for (int rr = 0; rr < 4; rr++) {
            int rl = wr * 64 + 16 * mt + 4 * hi + rr;
            float mean = (ssum[rl][0] + ssum[rl][1]) * (1.f / 192.f);
            float var = (ssq[rl][0] + ssq[rl][1]) * (1.f / 192.f) - mean * mean;
            float rstd = rsqrtf(var + 1e-5f);
            size_t rowg = m0 + rl;
            #pragma unroll
            for (int nt = 0; nt < 6; nt++) {
                float v = (acc[mt][nt][rr] - mean) * rstd * lgv[nt] + lbv[nt];
                yout[rowg * 192 + colg[nt]] = f2b(v);
            }
        }
}

// ---------------- window attention (MFMA, one wave per window-head) ----------
template<int SHIFT>
__global__ __launch_bounds__(128) void attn_k(const unsigned short* __restrict__ qkv,
                                              const float* __restrict__ pos,
                                              unsigned short* __restrict__ ao) {
    __shared__ float Pl[169];
    __shared__ unsigned short Pbuf[2][64 * 72];
    __shared__ unsigned short Vtb[2][32 * 72];
    int t = threadIdx.x;
    int wid = t >> 6, lane = t & 63;
    int iq = lane & 15, hi = lane >> 4;
    int idx = blockIdx.x * 2 + wid;
    int window = idx / 6, head = idx % 6;
    int b = window >> 10, wrem = window & 1023;
    int wi = wrem >> 5, wj = wrem & 31;

    for (int ii = t; ii < 169; ii += 128) Pl[ii] = pos[ii];
    __syncthreads();

    unsigned short* P  = Pbuf[wid];
    unsigned short* Vt = Vtb[wid];

    auto trow = [&](int p) -> size_t {
        int pi = p / 7, pj = p - pi * 7;
        int gi = wi * 7 + pi, gj = wj * 7 + pj;
        if (SHIFT) { gi += DISPL; if (gi >= HH) gi -= HH; gj += DISPL; if (gj >= WWID) gj -= WWID; }
        return ((size_t)b * HH + gi) * WWID + gj;
    };

    if (lane < 49) {
        size_t m = trow(lane);
        const unsigned short* vsrc = qkv + m * 576 + 2 * 192 + head * 32;
        #pragma unroll
        for (int c = 0; c < 4; c++) {
            uint4 vv = *(const uint4*)(vsrc + c * 8);
            const unsigned short* us = (const unsigned short*)&vv;
            #pragma unroll
            for (int e = 0; e < 8; e++) Vt[(c * 8 + e) * 72 + lane] = us[e];
        }
    } else {
        #pragma unroll
        for (int d = 0; d < 32; d++) Vt[d * 72 + lane] = 0;
    }

    short8v aK[4], bQ[4];
    #pragma unroll
    for (int tt = 0; tt < 4; tt++) {
        int p = 16 * tt + iq;
        short8v zq = {0,0,0,0,0,0,0,0}, zk = zq;
        if (p < 49) {
            size_t m = trow(p);
            const unsigned short* base = qkv + m * 576 + head * 32 + hi * 8;
            zq = *(const short8v*)(base);
            zk = *(const short8v*)(base + 192);
        }
        aK[tt] = zk; bQ[tt] = zq;
    }

    f32x4 st[4][4] = {};
    #pragma unroll
    for (int jt = 0; jt < 4; jt++)
        #pragma unroll
        for (int it = 0; it < 4; it++)
            st[jt][it] = __builtin_amdgcn_mfma_f32_16x16x32_bf16(aK[jt], bQ[it], st[jt][it], 0, 0, 0);

    const float scale = 0.17677669529663687f;
    #pragma unroll
    for (int it = 0; it < 4; it++) {
        int i = iq + 16 * it;
        int ic = i > 48 ? 48 : i;
        int ih = ic / 7, iw2 = ic - ih * 7;
        float sv[16];
        #pragma unroll
        for (int jt = 0; jt < 4; jt++) {
            #pragma unroll
            for (int r = 0; r < 4; r++) {
                int jj = 16 * jt + 4 * hi + r;
                float s;
                if (jj < 49) {
                    int jh = jj / 7, jw2 = jj - jh * 7;
                    s = st[jt][it][r] * scale + Pl[(jh - ih + 6) * 13 + (jw2 - iw2 + 6)];
                    if (SHIFT) {
                        bool msk = false;
                        if (wi == 31) msk = msk || ((i >= 28) != (jj >= 28));
                        if (wj == 31) msk = msk || ((iw2 >= 4) != (jw2 >= 4));
                        if (msk) s = -1e30f;
                    }
                } else s = -1e30f;
                sv[jt * 4 + r] = s;
            }
        }
        float mx = sv[0];
        #pragma unroll
        for (int u = 1; u < 16; u++) mx = fmaxf(mx, sv[u]);
        mx = fmaxf(mx, __shfl_xor(mx, 16));
        mx = fmaxf(mx, __shfl_xor(mx, 32));
        float sum = 0.f;
        #pragma unroll
        for (int u = 0; u < 16; u++) { sv[u] = __expf(sv[u] - mx); sum += sv[u]; }
        sum += __shfl_xor(sum, 16);
        sum += __shfl_xor(sum, 32);
        float rinv = 1.0f / sum;
        #pragma unroll
        for (int jt = 0; jt < 4; jt++) {
            ushort4 w4;
            w4.x = f2b(sv[jt * 4 + 0] * rinv);
            w4.y = f2b(sv[jt * 4 + 1] * rinv);
            w4.z = f2b(sv[jt * 4 + 2] * rinv);
            w4.w = f2b(sv[jt * 4 + 3] * rinv);
            *(ushort4*)&P[i * 72 + 16 * jt + 4 * hi] = w4;
        }
    }

    f32x4 o[4][2] = {};
    #pragma unroll
    for (int ks = 0; ks < 2; ks++) {
        short8v bV[2], aP[4];
        #pragma unroll
        for (int nt = 0; nt < 2; nt++)
            bV[nt] = *(const short8v*)&Vt[(iq + 16 * nt) * 72 + 32 * ks + 8 * hi];
        #pragma unroll
        for (int mt = 0; mt < 4; mt++)
            aP[mt] = *(const short8v*)&P[(iq + 16 * mt) * 72 + 32 * ks + 8 * hi];
        #pragma unroll
        for (int mt = 0; mt < 4; mt++)
            #pragma unroll
            for (int nt = 0; nt < 2; nt++)
                o[mt][nt] = __builtin_amdgcn_mfma_f32_16x16x32_bf16(aP[mt], bV[nt], o[mt][nt], 0, 0, 0);
    }

    #pragma unroll
    for (int mt = 0; mt < 4; mt++) {
        #pragma unroll
        for (int r = 0; r < 4; r++) {
            int i = 16 * mt + 4 * hi + r;
            if (i < 49) {
                size_t m = trow(i);
                unsigned short* dst = ao + m * 192 + head * 32 + iq;
                dst[0]  = f2b(o[mt][0][r]);
                dst[16] = f2b(o[mt][1][r]);
            }
        }
    }
}

// ---------------- final transpose: t[2][224][224][192] -> out[2][192][224][224]
__global__ __launch_bounds__(256) void tr_k(const float* __restrict__ tin,
                                            float* __restrict__ outp) {
    __shared__ float tile[32][33];
    int bi = blockIdx.x;
    int j0 = blockIdx.y * 32, c0 = blockIdx.z * 32;
    int t = threadIdx.x;
    int tx = t & 31, ty = t >> 5;
    int b = bi / 224, i = bi % 224;
    #pragma unroll
    for (int yy = 0; yy < 32; yy += 8) {
        int j = j0 + ty + yy;
        tile[ty + yy][tx] = tin[((size_t)bi * 224 + j) * 192 + c0 + tx];
    }
    __syncthreads();
    #pragma unroll
    for (int yy = 0; yy < 32; yy += 8) {
        int c = c0 + ty + yy;
        outp[(((size_t)b * 192 + c) * 224 + i) * 224 + j0 + tx] = tile[tx][ty + yy];
    }
}

extern "C" void kernel_launch(void* const* d_in, const int* in_sizes, int n_in,
                              void* d_out, int out_size, void* d_ws, size_t ws_size,
                              hipStream_t stream) {
    (void)in_sizes; (void)n_in; (void)out_size; (void)ws_size;
    const float* x    = (const float*)d_in[0];
    const float* pm_w = (const float*)d_in[1];
    const float* pm_b = (const float*)d_in[2];

    const size_t M = MROWS;
    char* ws = (char*)d_ws;
    size_t off = 0;
    float* tbuf = (float*)(ws + off);           off += M * 192 * 4;
    unsigned short* ybuf = (unsigned short*)(ws + off); off += M * 192 * 2;
    unsigned short* big  = (unsigned short*)(ws + off); off += M * 768 * 2;
    unsigned short* pm_wt = (unsigned short*)(ws + off); off += 192 * 384 * 2;
    unsigned short* wqkv_t[2]; unsigned short* wo_t[2];
    unsigned short* w1_t[2];   unsigned short* w2_t[2];
    for (int s = 0; s < 2; s++) {
        wqkv_t[s] = (unsigned short*)(ws + off); off += 576 * 192 * 2;
        wo_t[s]   = (unsigned short*)(ws + off); off += 192 * 192 * 2;
        w1_t[s]   = (unsigned short*)(ws + off); off += 768 * 192 * 2;
        w2_t[s]   = (unsigned short*)(ws + off); off += 192 * 768 * 2;
    }
    unsigned short* qkv = big;
    unsigned short* hbf = big;
    unsigned short* ao  = ybuf;

    auto wt = [&](const float* W, unsigned short* Wt, int K, int N) {
        int n = K * N;
        wt_k<<<(n + 255) / 256, 256, 0, stream>>>(W, Wt, K, N);
    };
    wt(pm_w, pm_wt, 384, 192);
    for (int s = 0; s < 2; s++) {
        wt((const float*)d_in[5 + 12 * s],  wqkv_t[s], 192, 576);
        wt((const float*)d_in[7 + 12 * s],  wo_t[s],   192, 192);
        wt((const float*)d_in[11 + 12 * s], w1_t[s],   192, 768);
        wt((const float*)d_in[13 + 12 * s], w2_t[s],   768, 192);
    }

    // fused unfold + patch-merge GEMM + LN1(r)
    pm_gemm_k<<<MROWS / 128, 256, 0, stream>>>(x, pm_wt, pm_b,
        (const float*)d_in[3], (const float*)d_in[4], tbuf, ybuf);

    for (int s = 0; s < 2; s++) {
        const float* pos  = (const float*)d_in[6 + 12 * s];
        const float* bo   = (const float*)d_in[8 + 12 * s];
        const float* ln2g = (const float*)d_in[9 + 12 * s];
        const float* ln2b = (const float*)d_in[10 + 12 * s];
        const float* b1   = (const float*)d_in[12 + 12 * s];
        const float* b2   = (const float*)d_in[14 + 12 * s];

        gemm_k<0, 0, 0><<<dim3(3, MROWS / 128), 256, 0, stream>>>(
            ybuf, wqkv_t[s], nullptr, nullptr, nullptr, nullptr, nullptr, qkv, 576, 192);
        if (s == 0) attn_k<0><<<2048 * NHEADS / 2, 128, 0, stream>>>(qkv, pos, ao);
        else        attn_k<1><<<2048 * NHEADS / 2, 128, 0, stream>>>(qkv, pos, ao);
        gemm_k<2, 1, 1><<<dim3(1, MROWS / 128), 256, 0, stream>>>(
            ao, wo_t[s], bo, tbuf, ln2g, ln2b, tbuf, ybuf, 192, 192);
        gemm_k<1, 1, 0><<<dim3(4, MROWS / 128), 256, 0, stream>>>(
            ybuf, w1_t[s], b1, nullptr, nullptr, nullptr, nullptr, hbf, 768, 192);
        if (s == 0) {
            gemm_k<2, 1, 1><<<dim3(1, MROWS / 128), 256, 0, stream>>>(
                hbf, w2_t[0], b2, tbuf, (const float*)d_in[15], (const float*)d_in[16],
                tbuf, ybuf, 192, 768);
        } else {
            gemm_k<3, 1, 1><<<dim3(1, MROWS / 128), 256, 0, stream>>>(
                hbf, w2_t[1], b2, tbuf, nullptr, nullptr, tbuf, nullptr, 192, 768);
        }
    }

    tr_k<<<dim3(NB * 224, 7, 6), 256, 0, stream>>>(tbuf, (float*)d_out);
}